// Round 6
// baseline (293.463 us; speedup 1.0000x reference)
//
#include <hip/hip_runtime.h>
#include <hip/hip_bf16.h>

#define D 512
#define D4 (D / 4)
#define ND 4
#define EPSF 1e-3f
#define SROWS 32  // rows per stats block -> 2048 blocks at B=65536
#define NROWS 32  // rows per norm block  -> 2048 blocks

// ---------------------------------------------------------------------------
// Kernel A: per-row domain id (argmax of one-hot, first-max-wins) + counts.
// ---------------------------------------------------------------------------
__global__ __launch_bounds__(256) void dom_kernel(const float4* __restrict__ ind,
                                                  unsigned char* __restrict__ dom,
                                                  float* __restrict__ cnt, int B) {
  __shared__ int lc[ND];
  const int t = threadIdx.x;
  if (t < ND) lc[t] = 0;
  __syncthreads();
  const int i = blockIdx.x * blockDim.x + t;
  if (i < B) {
    float4 v = ind[i];
    int d = 0;
    float best = v.x;
    if (v.y > best) { best = v.y; d = 1; }
    if (v.z > best) { best = v.z; d = 2; }
    if (v.w > best) { best = v.w; d = 3; }
    dom[i] = (unsigned char)d;
    atomicAdd(&lc[d], 1);
  }
  __syncthreads();
  if (t < ND && lc[t]) atomicAdd(&cnt[t], (float)lc[t]);
}

// Dom byte for compile-time even index bi in [0,32) within the block's 32-row
// chunk (uint4s dva/dvb); actual row = base + bi + rg via the rsh byte shift.
// NO readfirstlane, NO branches -> pure VALU, never blocks load hoisting.
#define DOMW(bi)                                                               \
  ((bi) < 4 ? dva.x : (bi) < 8 ? dva.y : (bi) < 12 ? dva.z : (bi) < 16         \
   ? dva.w : (bi) < 20 ? dvb.x : (bi) < 24 ? dvb.y : (bi) < 28 ? dvb.z : dvb.w)
#define DOMB(bi) ((int)((DOMW(bi) >> (8 * ((bi) & 3) + rsh)) & 3))

#define LOAD4(c)                                                               \
  v0 = xp[(size_t)((c) + 0) * D4]; v1 = xp[(size_t)((c) + 2) * D4];            \
  v2 = xp[(size_t)((c) + 4) * D4]; v3 = xp[(size_t)((c) + 6) * D4];

// ---------------------------------------------------------------------------
// Kernel B: per-domain per-column sum & sqsum -> per-block partials.
// BRANCHLESS predicated accumulate: no control flow between loads and uses,
// so the scheduler keeps 4 float4 loads in flight per thread.
// Partial layout (float4): partial[b*1024 + (rg?512:0) + dd*128 + tc].
// ---------------------------------------------------------------------------
__global__ __launch_bounds__(256, 4) void stats_kernel(
    const float4* __restrict__ x, const unsigned char* __restrict__ dom,
    float4* __restrict__ partial, int B) {
  const int t = threadIdx.x;
  const int tc = t & 127;
  const int rg = t >> 7;
  const int base = blockIdx.x * SROWS;
  const int rsh = 8 * rg;

  float4 s0 = make_float4(0.f, 0.f, 0.f, 0.f), s1 = s0, s2 = s0, s3 = s0;
  float4 q0 = s0, q1 = s0, q2 = s0, q3 = s0;
  float4 v0, v1, v2, v3;

// Predicated accumulate: m = pred ? v : 0; s += m; q = fma(m, v, q).
#define ACCP(sd, qd, v, p)                                                     \
  do {                                                                         \
    const float m0 = (p) ? (v).x : 0.f, m1 = (p) ? (v).y : 0.f;                \
    const float m2 = (p) ? (v).z : 0.f, m3 = (p) ? (v).w : 0.f;                \
    (sd).x += m0; (sd).y += m1; (sd).z += m2; (sd).w += m3;                    \
    (qd).x = fmaf(m0, (v).x, (qd).x); (qd).y = fmaf(m1, (v).y, (qd).y);        \
    (qd).z = fmaf(m2, (v).z, (qd).z); (qd).w = fmaf(m3, (v).w, (qd).w);        \
  } while (0)
#define ROWP(v, d)                                                             \
  do {                                                                         \
    const int _d = (d);                                                        \
    ACCP(s0, q0, v, _d == 0); ACCP(s1, q1, v, _d == 1);                        \
    ACCP(s2, q2, v, _d == 2); ACCP(s3, q3, v, _d == 3);                        \
  } while (0)

  if (base + SROWS <= B) {
    const uint4* dp = (const uint4*)(dom + base);
    const uint4 dva = dp[0];
    const uint4 dvb = dp[1];
    const float4* xp = x + (size_t)(base + rg) * D4 + tc;
#pragma unroll
    for (int it = 0; it < SROWS; it += 8) {  // 4 rows per rg per burst
      LOAD4(it);
      ROWP(v0, DOMB(it + 0));
      ROWP(v1, DOMB(it + 2));
      ROWP(v2, DOMB(it + 4));
      ROWP(v3, DOMB(it + 6));
    }
  } else {  // tail (not hit when B % SROWS == 0)
    for (int it = 0; it < SROWS; it += 2) {
      const int r = base + it + rg;
      if (r < B) {
        const int d = (int)dom[r];
        float4 v = x[(size_t)r * D4 + tc];
        ROWP(v, d);
      }
    }
  }

  // Cross-row-group reduce via LDS (stride 33 -> conflict-free), then plain
  // coalesced partial stores: rg0 writes sums, rg1 writes sqs.
  __shared__ float red[128 * 33];
  float* p = &red[tc * 33];
#define STV(k, v)                                                              \
  do { p[(k)] = (v).x; p[(k) + 1] = (v).y; p[(k) + 2] = (v).z;                 \
       p[(k) + 3] = (v).w; } while (0)
  if (rg == 1) {
    STV(0, s0); STV(4, s1); STV(8, s2); STV(12, s3);
  } else {
    STV(16, q0); STV(20, q1); STV(24, q2); STV(28, q3);
  }
  __syncthreads();
  float4* pout = partial + (size_t)blockIdx.x * 1024 + (rg ? 512 : 0) + tc;
#define OUTV(k, v, dd)                                                         \
  do {                                                                         \
    float4 o;                                                                  \
    o.x = (v).x + p[(k)];     o.y = (v).y + p[(k) + 1];                        \
    o.z = (v).z + p[(k) + 2]; o.w = (v).w + p[(k) + 3];                        \
    pout[(dd)*128] = o;                                                        \
  } while (0)
  if (rg == 0) {
    OUTV(0, s0, 0); OUTV(4, s1, 1); OUTV(8, s2, 2); OUTV(12, s3, 3);
  } else {
    OUTV(16, q0, 0); OUTV(20, q1, 1); OUTV(24, q2, 2); OUTV(28, q3, 3);
  }
}

// ---------------------------------------------------------------------------
// Kernel B2: reduce nb per-block partials (1024 float4 each) into accum[4096].
// Grid = 4 j-groups x 64 b-groups = 256 blocks; float4 loads; depth-64 atomics.
// ---------------------------------------------------------------------------
__global__ __launch_bounds__(256) void reduce_kernel(const float4* __restrict__ partial,
                                                     float* __restrict__ accum, int nb) {
  const int jg = blockIdx.x & 3;
  const int bg = blockIdx.x >> 2;
  const int nbg = gridDim.x >> 2;
  const int chunk = (nb + nbg - 1) / nbg;
  const int j4 = jg * 256 + threadIdx.x;  // float4 index in [0,1024)
  const int b0 = bg * chunk;
  const int b1 = min(b0 + chunk, nb);
  float4 acc = make_float4(0.f, 0.f, 0.f, 0.f);
  for (int b = b0; b < b1; ++b) {
    float4 v = partial[(size_t)b * 1024 + j4];
    acc.x += v.x; acc.y += v.y; acc.z += v.z; acc.w += v.w;
  }
  atomicAdd(&accum[j4 * 4 + 0], acc.x);
  atomicAdd(&accum[j4 * 4 + 1], acc.y);
  atomicAdd(&accum[j4 * 4 + 2], acc.z);
  atomicAdd(&accum[j4 * 4 + 3], acc.w);
}

// ---------------------------------------------------------------------------
// Kernel C: finalize -> inv = gamma * rsqrt(var + eps), shift = beta - mean*inv.
// ---------------------------------------------------------------------------
__global__ __launch_bounds__(256) void fin_kernel(const float* __restrict__ sums,
                                                  const float* __restrict__ sqs,
                                                  const float* __restrict__ cnt,
                                                  const float* __restrict__ gamma,
                                                  const float* __restrict__ beta,
                                                  float* __restrict__ inv,
                                                  float* __restrict__ shf) {
  const int i = blockIdx.x * blockDim.x + threadIdx.x;
  if (i < ND * D) {
    const int d = i >> 9;  // /512
    const float c = fmaxf(cnt[d], 1.0f);
    const float m = sums[i] / c;
    const float va = sqs[i] / c - m * m;  // biased variance
    const float iv = gamma[i] * rsqrtf(va + EPSF);
    inv[i] = iv;
    shf[i] = beta[i] - m * iv;
  }
}

// ---------------------------------------------------------------------------
// Kernel D: out = fma(x, inv[dom], shift[dom]).
// Register-resident 4-domain table; BRANCHLESS component-wise ternary select
// (v_cndmask) so loads stay hoisted; 4 loads in flight.
// ---------------------------------------------------------------------------
__global__ __launch_bounds__(256, 4) void norm_kernel(const float4* __restrict__ x,
                                                      const unsigned char* __restrict__ dom,
                                                      const float4* __restrict__ inv,
                                                      const float4* __restrict__ shf,
                                                      float4* __restrict__ out, int B) {
  const int t = threadIdx.x;
  const int tc = t & 127;
  const int rg = t >> 7;
  const int base = blockIdx.x * NROWS;
  const int rsh = 8 * rg;

  const float4 A0 = inv[0 * D4 + tc], A1 = inv[1 * D4 + tc];
  const float4 A2 = inv[2 * D4 + tc], A3 = inv[3 * D4 + tc];
  const float4 B0 = shf[0 * D4 + tc], B1 = shf[1 * D4 + tc];
  const float4 B2 = shf[2 * D4 + tc], B3 = shf[3 * D4 + tc];

#define SELA(c, d) ((d) == 0 ? A0.c : (d) == 1 ? A1.c : (d) == 2 ? A2.c : A3.c)
#define SELB(c, d) ((d) == 0 ? B0.c : (d) == 1 ? B1.c : (d) == 2 ? B2.c : B3.c)
#define NROWP(v, bi)                                                           \
  do {                                                                         \
    const int _d = DOMB(bi);                                                   \
    float4 o;                                                                  \
    o.x = fmaf((v).x, SELA(x, _d), SELB(x, _d));                               \
    o.y = fmaf((v).y, SELA(y, _d), SELB(y, _d));                               \
    o.z = fmaf((v).z, SELA(z, _d), SELB(z, _d));                               \
    o.w = fmaf((v).w, SELA(w, _d), SELB(w, _d));                               \
    op[(size_t)(bi)*D4] = o;                                                   \
  } while (0)

  if (base + NROWS <= B) {
    const uint4* dp = (const uint4*)(dom + base);
    const uint4 dva = dp[0];
    const uint4 dvb = dp[1];
    const float4* xp = x + (size_t)(base + rg) * D4 + tc;
    float4* op = out + (size_t)(base + rg) * D4 + tc;
    float4 v0, v1, v2, v3;
#pragma unroll
    for (int it = 0; it < NROWS; it += 8) {
      LOAD4(it);
      NROWP(v0, it + 0);
      NROWP(v1, it + 2);
      NROWP(v2, it + 4);
      NROWP(v3, it + 6);
    }
  } else {  // tail
    for (int it = 0; it < NROWS; it += 2) {
      const int r = base + it + rg;
      if (r < B) {
        const int _d = (int)dom[r];
        float4 v = x[(size_t)r * D4 + tc];
        float4 o;
        o.x = fmaf(v.x, SELA(x, _d), SELB(x, _d));
        o.y = fmaf(v.y, SELA(y, _d), SELB(y, _d));
        o.z = fmaf(v.z, SELA(z, _d), SELB(z, _d));
        o.w = fmaf(v.w, SELA(w, _d), SELB(w, _d));
        out[(size_t)r * D4 + tc] = o;
      }
    }
  }
}

extern "C" void kernel_launch(void* const* d_in, const int* in_sizes, int n_in,
                              void* d_out, int out_size, void* d_ws, size_t ws_size,
                              hipStream_t stream) {
  const float* x = (const float*)d_in[0];
  const float* ind = (const float*)d_in[1];
  const float* gamma = (const float*)d_in[2];
  const float* beta = (const float*)d_in[3];
  float* out = (float*)d_out;
  const int B = in_sizes[0] / D;

  // Workspace layout (bytes):
  //   [0,16)        cnt[ND]
  //   [256,16640)   accum[4096]  (sums[2048] || sqs[2048])
  //   [16640,24832) inv[ND*D]
  //   [24832,33024) shf[ND*D]
  //   [33024,...)   dom[B] uint8
  // Per-block stats partials (nblk_s * 16 KiB) live in d_out, which norm_kernel
  // fully overwrites afterwards (same stream -> ordered).
  char* ws = (char*)d_ws;
  float* cnt = (float*)(ws + 0);
  float* accum = (float*)(ws + 256);
  float* inv = (float*)(ws + 256 + 16384);
  float* shf = (float*)(ws + 256 + 24576);
  unsigned char* dom = (unsigned char*)(ws + 256 + 32768);

  // cnt + accum must start at zero (ws is poisoned 0xAA before every call).
  (void)hipMemsetAsync(d_ws, 0, 256 + 16384, stream);

  dom_kernel<<<(B + 255) / 256, 256, 0, stream>>>((const float4*)ind, dom, cnt, B);

  const int nblk_s = (B + SROWS - 1) / SROWS;  // 2048 at B=65536
  stats_kernel<<<nblk_s, 256, 0, stream>>>((const float4*)x, dom, (float4*)out, B);

  reduce_kernel<<<256, 256, 0, stream>>>((const float4*)out, accum, nblk_s);

  fin_kernel<<<(ND * D + 255) / 256, 256, 0, stream>>>(accum, accum + 2048, cnt,
                                                       gamma, beta, inv, shf);

  norm_kernel<<<(B + NROWS - 1) / NROWS, 256, 0, stream>>>(
      (const float4*)x, dom, (const float4*)inv, (const float4*)shf, (float4*)out, B);
}